// Round 5
// baseline (197.312 us; speedup 1.0000x reference)
//
#include <hip/hip_runtime.h>

// Problem constants (fixed by the reference)
#define BATCH 128
#define C 64
#define L 4096
#define K 31

// ---- Kernel 1 tiling: 1024 blocks (8 tiles x 128 b), 256 threads = 4 waves.
// Wave computes the full 512-output tile partial over its 16 channels
// (2-deep software-pipelined register windows), 4-way LDS reduce, store S.
#define NT 256
#define NWAVE 4
#define CPW (C / NWAVE)           // 16 channels per wave
#define R 8                       // outputs per lane
#define TILE 512                  // 64 lanes * R
#define WIN 40                    // aligned window [l0-16, l0+24)

typedef float floatx4 __attribute__((ext_vector_type(4)));
typedef float floatx2 __attribute__((ext_vector_type(2)));

// S[b,l] = sum_i sum_k w[i,k] * x[b,i,l+15-k]   (x zero outside [0,L))
__global__ __launch_bounds__(NT, 4)
void computeS_kernel(const float* __restrict__ x,
                     const float* __restrict__ w,
                     float* __restrict__ S) {
    __shared__ __align__(16) float psum[NWAVE][TILE];

    const int tid  = threadIdx.x;
    const int wave = tid >> 6;
    const int lane = tid & 63;
    const int tile = blockIdx.x;          // 0..7
    const int b    = blockIdx.y;          // 0..127
    const int lt   = lane * R;            // within-tile output start
    const int l0   = tile * TILE + lt;    // global output start

    const float* xb = x + (long)b * C * L;
    const int i0 = wave * CPW;

    float acc[R];
#pragma unroll
    for (int r = 0; r < R; ++r) acc[r] = 0.f;

    const bool interior = (l0 >= 16) && (l0 + 24 <= L);

    if (interior) {
        const float* xw = xb + (l0 - 16);   // 16B-aligned (l0 % 8 == 0)
        float winA[WIN], winB[WIN];
        {
            const floatx4* p = reinterpret_cast<const floatx4*>(xw + (long)i0 * L);
#pragma unroll
            for (int j = 0; j < WIN / 4; ++j)
                reinterpret_cast<floatx4*>(winA)[j] = p[j];
        }
        for (int c = 0; c < CPW; c += 2) {
            {   // prefetch channel c+1 into winB
                const floatx4* p = reinterpret_cast<const floatx4*>(xw + (long)(i0 + c + 1) * L);
#pragma unroll
                for (int j = 0; j < WIN / 4; ++j)
                    reinterpret_cast<floatx4*>(winB)[j] = p[j];
            }
            {   // compute channel c from winA
                const float* wp = w + (i0 + c) * K;   // wave-uniform -> s_load
#pragma unroll
                for (int k = 0; k < K; ++k) {
                    const float wk = wp[k];
#pragma unroll
                    for (int r = 0; r < R; ++r)
                        acc[r] += wk * winA[r + 31 - k];
                }
            }
            if (c + 2 < CPW) {   // prefetch channel c+2 into winA
                const floatx4* p = reinterpret_cast<const floatx4*>(xw + (long)(i0 + c + 2) * L);
#pragma unroll
                for (int j = 0; j < WIN / 4; ++j)
                    reinterpret_cast<floatx4*>(winA)[j] = p[j];
            }
            {   // compute channel c+1 from winB
                const float* wp = w + (i0 + c + 1) * K;
#pragma unroll
                for (int k = 0; k < K; ++k) {
                    const float wk = wp[k];
#pragma unroll
                    for (int r = 0; r < R; ++r)
                        acc[r] += wk * winB[r + 31 - k];
                }
            }
        }
    } else {
        // Edge lanes: guarded scalar loads.
        for (int c = 0; c < CPW; ++c) {
            const float* xi = xb + (long)(i0 + c) * L;
            float win[WIN];
#pragma unroll
            for (int j = 0; j < WIN; ++j) {
                const int g = l0 - 16 + j;
                win[j] = (g >= 0 && g < L) ? xi[g] : 0.f;
            }
            const float* wp = w + (i0 + c) * K;
#pragma unroll
            for (int k = 0; k < K; ++k) {
                const float wk = wp[k];
#pragma unroll
                for (int r = 0; r < R; ++r)
                    acc[r] += wk * win[r + 31 - k];
            }
        }
    }

    // 4-way cross-wave reduction, then tiny S store (2 KB per block).
#pragma unroll
    for (int r = 0; r < R; r += 4) {
        floatx4 a; a.x = acc[r]; a.y = acc[r+1]; a.z = acc[r+2]; a.w = acc[r+3];
        *reinterpret_cast<floatx4*>(&psum[wave][lt + r]) = a;
    }
    __syncthreads();
    {
        const int e = tid * 2;
        floatx2 s;
        s.x = psum[0][e]   + psum[1][e]   + psum[2][e]   + psum[3][e];
        s.y = psum[0][e+1] + psum[1][e+1] + psum[2][e+1] + psum[3][e+1];
        *reinterpret_cast<floatx2*>(&S[(long)b * L + tile * TILE + e]) = s;
    }
}

// ---- Kernel 2: out[b,o,l] = S[b,l] — pure dense stream write.
// 2048 blocks x 256 threads, grid-stride over B*C*L/4 float4s (16 iters).
#define NB2 2048
__global__ __launch_bounds__(NT)
void broadcast_kernel(const float* __restrict__ S,
                      float* __restrict__ out) {
    const long total = (long)BATCH * C * (L / 4);
    const long stride = (long)NB2 * NT;
    for (long f = blockIdx.x * (long)NT + threadIdx.x; f < total; f += stride) {
        const int l4 = (int)(f & (L / 4 - 1));        // f % 1024
        const long b = f >> 16;                        // f / (C*L/4)
        const floatx4 v = *reinterpret_cast<const floatx4*>(S + (b << 12) + (l4 << 2));
        __builtin_nontemporal_store(v, reinterpret_cast<floatx4*>(out + f * 4));
    }
}

// ---- Fallback (proven round-3 fused kernel) if ws_size < 2 MB ----
#define FB_R 4
#define FB_TILE (NT * FB_R)
#define FB_WIN 36
__global__ __launch_bounds__(NT)
void fused_kernel(const float* __restrict__ x,
                  const float* __restrict__ w,
                  float* __restrict__ out) {
    const int tid = threadIdx.x;
    const int tile = blockIdx.x;
    const int b = blockIdx.y;
    const int l0 = tile * FB_TILE + tid * FB_R;
    float acc[FB_R] = {0.f, 0.f, 0.f, 0.f};
    const float* xb = x + (long)b * C * L;
    const bool interior = (l0 >= 16) && (l0 + 20 <= L);
    if (interior) {
        const float* xw = xb + (l0 - 16);
#pragma unroll 2
        for (int i = 0; i < C; ++i) {
            float win[FB_WIN];
            const floatx4* p = reinterpret_cast<const floatx4*>(xw + (long)i * L);
#pragma unroll
            for (int j = 0; j < FB_WIN / 4; ++j)
                reinterpret_cast<floatx4*>(win)[j] = p[j];
            const float* wp = w + i * K;
#pragma unroll
            for (int k = 0; k < K; ++k) {
                const float wk = wp[k];
#pragma unroll
                for (int r = 0; r < FB_R; ++r)
                    acc[r] += wk * win[r + 31 - k];
            }
        }
    } else {
        for (int i = 0; i < C; ++i) {
            const float* xi = xb + (long)i * L;
            float win[FB_WIN];
#pragma unroll
            for (int j = 0; j < FB_WIN; ++j) {
                const int g = l0 - 16 + j;
                win[j] = (g >= 0 && g < L) ? xi[g] : 0.f;
            }
            const float* wp = w + i * K;
#pragma unroll
            for (int k = 0; k < K; ++k) {
                const float wk = wp[k];
#pragma unroll
                for (int r = 0; r < FB_R; ++r)
                    acc[r] += wk * win[r + 31 - k];
            }
        }
    }
    float* op = out + (long)b * C * L + l0;
    floatx4 v; v.x = acc[0]; v.y = acc[1]; v.z = acc[2]; v.w = acc[3];
#pragma unroll
    for (int o = 0; o < C; ++o)
        __builtin_nontemporal_store(v, reinterpret_cast<floatx4*>(op + (long)o * L));
}

extern "C" void kernel_launch(void* const* d_in, const int* in_sizes, int n_in,
                              void* d_out, int out_size, void* d_ws, size_t ws_size,
                              hipStream_t stream) {
    const float* x = (const float*)d_in[0];   // [B, C, L] fp32
    const float* w = (const float*)d_in[1];   // [C, C, K] fp32; o=0 slice used
    float* out = (float*)d_out;               // [B, C, L] fp32

    const size_t s_bytes = (size_t)BATCH * L * sizeof(float);   // 2 MB
    if (ws_size >= s_bytes) {
        float* S = (float*)d_ws;
        dim3 grid1(L / TILE, BATCH);
        computeS_kernel<<<grid1, NT, 0, stream>>>(x, w, S);
        broadcast_kernel<<<NB2, NT, 0, stream>>>(S, out);
    } else {
        dim3 grid(L / FB_TILE, BATCH);
        fused_kernel<<<grid, NT, 0, stream>>>(x, w, out);
    }
}

// Round 6
// 150.181 us; speedup vs baseline: 1.3138x; 1.3138x over previous
//
#include <hip/hip_runtime.h>

// Problem constants (fixed by the reference)
#define BATCH 128
#define C 64
#define L 4096
#define K 31

#define NT 256
#define R 4                        // outputs per thread (K1)
#define TILE (NT * R)              // 1024 outputs per block
#define WIN 36                     // aligned window [l0-16, l0+20)
#define CG 4                       // channel groups (blocks split over channels)
#define CPB (C / CG)               // 16 channels per block

typedef float floatx4 __attribute__((ext_vector_type(4)));

// ---- K1: partial sums. Sp[cg][b][l] = sum_{i in group cg} sum_k w[i,k]*x[b,i,l+15-k]
// Round-3 compute structure (sequential channel walk, overlapping register
// windows, L1 absorbs the 7.5x request amplification), but 4x more blocks via
// the channel-group split -> 8 waves/SIMD to hide miss latency.
__global__ __launch_bounds__(NT, 8)
void computeS_kernel(const float* __restrict__ x,
                     const float* __restrict__ w,
                     float* __restrict__ Sp) {
    const int tid  = threadIdx.x;
    const int tile = blockIdx.x;          // 0..3
    const int b    = blockIdx.y;          // 0..127
    const int cg   = blockIdx.z;          // 0..3
    const int l0   = tile * TILE + tid * R;
    const int i0   = cg * CPB;

    float acc[R] = {0.f, 0.f, 0.f, 0.f};
    const float* xb = x + (long)b * C * L;
    const bool interior = (l0 >= 16) && (l0 + 20 <= L);

    if (interior) {
        const float* xw = xb + (l0 - 16);   // 16B-aligned (l0 % 4 == 0)
#pragma unroll 2
        for (int c = 0; c < CPB; ++c) {
            const int i = i0 + c;
            float win[WIN];
            const floatx4* p = reinterpret_cast<const floatx4*>(xw + (long)i * L);
#pragma unroll
            for (int j = 0; j < WIN / 4; ++j)
                reinterpret_cast<floatx4*>(win)[j] = p[j];

            const float* wp = w + i * K;    // wave-uniform -> scalar loads
#pragma unroll
            for (int k = 0; k < K; ++k) {
                const float wk = wp[k];
#pragma unroll
                for (int r = 0; r < R; ++r)
                    acc[r] += wk * win[r + 31 - k];   // win[j] = x[l0-16+j]
            }
        }
    } else {
        // Edge threads (8 per (b,cg)): guarded scalar loads.
        for (int c = 0; c < CPB; ++c) {
            const int i = i0 + c;
            const float* xi = xb + (long)i * L;
            float win[WIN];
#pragma unroll
            for (int j = 0; j < WIN; ++j) {
                const int g = l0 - 16 + j;
                win[j] = (g >= 0 && g < L) ? xi[g] : 0.f;
            }
            const float* wp = w + i * K;
#pragma unroll
            for (int k = 0; k < K; ++k) {
                const float wk = wp[k];
#pragma unroll
                for (int r = 0; r < R; ++r)
                    acc[r] += wk * win[r + 31 - k];
            }
        }
    }

    floatx4 v; v.x = acc[0]; v.y = acc[1]; v.z = acc[2]; v.w = acc[3];
    *reinterpret_cast<floatx4*>(Sp + ((long)cg * BATCH + b) * L + l0) = v;
}

// ---- K2: out[b,o,l] = sum_cg Sp[cg][b][l] — dense streaming broadcast.
// grid (L/256, BATCH); block: wave og handles o in [og*16, og*16+16),
// lane covers one float4 column. Sp reads are L2/L3-resident (8 MB).
__global__ __launch_bounds__(NT)
void broadcast_kernel(const float* __restrict__ Sp,
                      float* __restrict__ out) {
    const int lane = threadIdx.x & 63;
    const int og   = threadIdx.x >> 6;            // 0..3
    const int b    = blockIdx.y;
    const int l4   = blockIdx.x * 64 + lane;      // float4 column index
    const long sbase = (long)b * L + (long)l4 * 4;

    floatx4 v = *reinterpret_cast<const floatx4*>(Sp + sbase);
#pragma unroll
    for (int cg = 1; cg < CG; ++cg)
        v += *reinterpret_cast<const floatx4*>(Sp + (long)cg * BATCH * L + sbase);

    float* ob = out + ((long)b * C + og * 16) * L + (long)l4 * 4;
#pragma unroll
    for (int o = 0; o < 16; ++o)
        __builtin_nontemporal_store(v, reinterpret_cast<floatx4*>(ob + (long)o * L));
}

// ---- Fallback (proven round-3 fused kernel) if ws_size < 8 MB ----
__global__ __launch_bounds__(NT)
void fused_kernel(const float* __restrict__ x,
                  const float* __restrict__ w,
                  float* __restrict__ out) {
    const int tid = threadIdx.x;
    const int tile = blockIdx.x;
    const int b = blockIdx.y;
    const int l0 = tile * TILE + tid * R;
    float acc[R] = {0.f, 0.f, 0.f, 0.f};
    const float* xb = x + (long)b * C * L;
    const bool interior = (l0 >= 16) && (l0 + 20 <= L);
    if (interior) {
        const float* xw = xb + (l0 - 16);
#pragma unroll 2
        for (int i = 0; i < C; ++i) {
            float win[WIN];
            const floatx4* p = reinterpret_cast<const floatx4*>(xw + (long)i * L);
#pragma unroll
            for (int j = 0; j < WIN / 4; ++j)
                reinterpret_cast<floatx4*>(win)[j] = p[j];
            const float* wp = w + i * K;
#pragma unroll
            for (int k = 0; k < K; ++k) {
                const float wk = wp[k];
#pragma unroll
                for (int r = 0; r < R; ++r)
                    acc[r] += wk * win[r + 31 - k];
            }
        }
    } else {
        for (int i = 0; i < C; ++i) {
            const float* xi = xb + (long)i * L;
            float win[WIN];
#pragma unroll
            for (int j = 0; j < WIN; ++j) {
                const int g = l0 - 16 + j;
                win[j] = (g >= 0 && g < L) ? xi[g] : 0.f;
            }
            const float* wp = w + i * K;
#pragma unroll
            for (int k = 0; k < K; ++k) {
                const float wk = wp[k];
#pragma unroll
                for (int r = 0; r < R; ++r)
                    acc[r] += wk * win[r + 31 - k];
            }
        }
    }
    float* op = out + (long)b * C * L + l0;
    floatx4 v; v.x = acc[0]; v.y = acc[1]; v.z = acc[2]; v.w = acc[3];
#pragma unroll
    for (int o = 0; o < C; ++o)
        __builtin_nontemporal_store(v, reinterpret_cast<floatx4*>(op + (long)o * L));
}

extern "C" void kernel_launch(void* const* d_in, const int* in_sizes, int n_in,
                              void* d_out, int out_size, void* d_ws, size_t ws_size,
                              hipStream_t stream) {
    const float* x = (const float*)d_in[0];   // [B, C, L] fp32
    const float* w = (const float*)d_in[1];   // [C, C, K] fp32; o=0 slice used
    float* out = (float*)d_out;               // [B, C, L] fp32

    const size_t sp_bytes = (size_t)CG * BATCH * L * sizeof(float);   // 8 MB
    if (ws_size >= sp_bytes) {
        float* Sp = (float*)d_ws;
        dim3 grid1(L / TILE, BATCH, CG);          // 2048 blocks
        computeS_kernel<<<grid1, NT, 0, stream>>>(x, w, Sp);
        dim3 grid2(L / 256, BATCH);               // 2048 blocks
        broadcast_kernel<<<grid2, NT, 0, stream>>>(Sp, out);
    } else {
        dim3 grid(L / TILE, BATCH);
        fused_kernel<<<grid, NT, 0, stream>>>(x, w, out);
    }
}

// Round 7
// 68.259 us; speedup vs baseline: 2.8906x; 2.2002x over previous
//
#include <hip/hip_runtime.h>

// Problem constants (fixed by the reference)
#define BATCH 128
#define C 64
#define L 4096
#define K 31

#define NT 256
#define CG 4                 // channel groups (blocks split over channels)
#define CPB (C / CG)         // 16 channels per block
#define RW 8                 // outputs per lane
#define WTILE 512            // outputs per wave (64 lanes * RW)
#define BTILE 2048           // outputs per block (4 waves)

typedef float floatx4 __attribute__((ext_vector_type(4)));

__device__ __forceinline__ floatx4 ld4(const float* p) {
    return *reinterpret_cast<const floatx4*>(p);
}

// ---- K1: Sp[cg][b][l] = sum_{i in cg} sum_k w[i,k] * x[b,i,l+15-k]
// Amplification-free: each lane loads exactly its own 8 floats per channel
// (2 coalesced float4), window assembled via cross-lane shuffles; boundary
// lanes (0,1,62,63) patch via predicated halo loads.
__global__ __launch_bounds__(NT, 4)
void computeS_kernel(const float* __restrict__ x,
                     const float* __restrict__ w,
                     float* __restrict__ Sp) {
    const int tid  = threadIdx.x;
    const int wv   = tid >> 6;
    const int lane = tid & 63;
    const int tile = blockIdx.x;          // 0..1
    const int b    = blockIdx.y;          // 0..127
    const int cg   = blockIdx.z;          // 0..3
    const int W0   = tile * BTILE + wv * WTILE;   // wave's first output
    const int l0   = W0 + lane * RW;              // lane's first output
    const int i0   = cg * CPB;
    const float* xb = x + (long)b * C * L;

    const bool lo   = (lane < 2);
    const bool ln0  = (lane == 0);
    const bool hi   = (lane >= 62);
    const bool ln63 = (lane == 63);
    const bool leftOK  = (W0 > 0);             // wave-uniform
    const bool rightOK = (W0 + WTILE < L);     // wave-uniform

    float acc[RW];
#pragma unroll
    for (int r = 0; r < RW; ++r) acc[r] = 0.f;

    // prologue: own load for first channel
    floatx4 oa = ld4(xb + (long)i0 * L + l0);
    floatx4 ob = ld4(xb + (long)i0 * L + l0 + 4);

    for (int c = 0; c < CPB; ++c) {
        const int i = i0 + c;
        const float* xi = xb + (long)i * L;

        // halo loads for current channel (boundary lanes only; zeros at array edges)
        floatx4 hA0, hA1, hB0, hB1;
        hA0 = 0.f; hA1 = 0.f; hB0 = 0.f; hB1 = 0.f;
        if (lo && leftOK) {
            // lane0: hA=win[0..7]=x[W0-16..W0-9], hB=win[8..15]=x[W0-8..W0-1]
            // lane1: hA=win[0..7]=x[W0-8..W0-1]
            const float* hp = xi + l0 - 16;
            hA0 = ld4(hp); hA1 = ld4(hp + 4);
            if (ln0) { hB0 = ld4(hp + 8); hB1 = ld4(hp + 12); }
        }
        if (hi && rightOK) {
            // lane62: hA=win[32..39]=x[W0+512..519]
            // lane63: hA=win[32..39]=x[W0+520..527], hB=win[24..31]=x[W0+512..519]
            const float* hp = xi + W0 + WTILE;
            if (ln63) { hA0 = ld4(hp + 8); hA1 = ld4(hp + 12); hB0 = ld4(hp); hB1 = ld4(hp + 4); }
            else      { hA0 = ld4(hp);     hA1 = ld4(hp + 4); }
        }

        // prefetch next channel's own data (1-deep; TLP covers the rest)
        floatx4 na, nb;
        na = oa; nb = ob;
        if (c + 1 < CPB) {
            const float* np = xi + L + l0;   // channel i+1
            na = ld4(np); nb = ld4(np + 4);
        }

        // assemble window win[j] = x[l0 - 16 + j], j = 0..39
        float own[RW] = {oa.x, oa.y, oa.z, oa.w, ob.x, ob.y, ob.z, ob.w};
        float win[40];
#pragma unroll
        for (int j = 0; j < RW; ++j) {
            win[j]      = __shfl_up(own[j], 2, 64);   // lanes<2 fixed below
            win[8 + j]  = __shfl_up(own[j], 1, 64);   // lane0 fixed below
            win[16 + j] = own[j];
            win[24 + j] = __shfl_down(own[j], 1, 64); // lane63 fixed below
            win[32 + j] = __shfl_down(own[j], 2, 64); // lanes>=62 fixed below
        }
        if (lo) {
            win[0] = hA0.x; win[1] = hA0.y; win[2] = hA0.z; win[3] = hA0.w;
            win[4] = hA1.x; win[5] = hA1.y; win[6] = hA1.z; win[7] = hA1.w;
            if (ln0) {
                win[8]  = hB0.x; win[9]  = hB0.y; win[10] = hB0.z; win[11] = hB0.w;
                win[12] = hB1.x; win[13] = hB1.y; win[14] = hB1.z; win[15] = hB1.w;
            }
        }
        if (hi) {
            win[32] = hA0.x; win[33] = hA0.y; win[34] = hA0.z; win[35] = hA0.w;
            win[36] = hA1.x; win[37] = hA1.y; win[38] = hA1.z; win[39] = hA1.w;
            if (ln63) {
                win[24] = hB0.x; win[25] = hB0.y; win[26] = hB0.z; win[27] = hB0.w;
                win[28] = hB1.x; win[29] = hB1.y; win[30] = hB1.z; win[31] = hB1.w;
            }
        }

        const float* wp = w + i * K;   // wave-uniform -> scalar loads
#pragma unroll
        for (int k = 0; k < K; ++k) {
            const float wk = wp[k];
#pragma unroll
            for (int r = 0; r < RW; ++r)
                acc[r] += wk * win[r + 31 - k];
        }

        oa = na; ob = nb;
    }

    floatx4 v0, v1;
    v0.x = acc[0]; v0.y = acc[1]; v0.z = acc[2]; v0.w = acc[3];
    v1.x = acc[4]; v1.y = acc[5]; v1.z = acc[6]; v1.w = acc[7];
    float* sp = Sp + ((long)cg * BATCH + b) * L + l0;
    *reinterpret_cast<floatx4*>(sp) = v0;
    *reinterpret_cast<floatx4*>(sp + 4) = v1;
}

// ---- K2: out[b,o,l] = sum_cg Sp[cg][b][l] — dense streaming broadcast.
__global__ __launch_bounds__(NT)
void broadcast_kernel(const float* __restrict__ Sp,
                      float* __restrict__ out) {
    const int lane = threadIdx.x & 63;
    const int og   = threadIdx.x >> 6;            // 0..3
    const int b    = blockIdx.y;
    const int l4   = blockIdx.x * 64 + lane;      // float4 column index
    const long sbase = (long)b * L + (long)l4 * 4;

    floatx4 v = *reinterpret_cast<const floatx4*>(Sp + sbase);
#pragma unroll
    for (int cg = 1; cg < CG; ++cg)
        v += *reinterpret_cast<const floatx4*>(Sp + (long)cg * BATCH * L + sbase);

    float* ob = out + ((long)b * C + og * 16) * L + (long)l4 * 4;
#pragma unroll
    for (int o = 0; o < 16; ++o)
        __builtin_nontemporal_store(v, reinterpret_cast<floatx4*>(ob + (long)o * L));
}

// ---- Fallback (proven round-3 fused kernel) if ws_size < 8 MB ----
#define FB_R 4
#define FB_TILE (NT * FB_R)
#define FB_WIN 36
__global__ __launch_bounds__(NT)
void fused_kernel(const float* __restrict__ x,
                  const float* __restrict__ w,
                  float* __restrict__ out) {
    const int tid = threadIdx.x;
    const int tile = blockIdx.x;
    const int b = blockIdx.y;
    const int l0 = tile * FB_TILE + tid * FB_R;
    float acc[FB_R] = {0.f, 0.f, 0.f, 0.f};
    const float* xb = x + (long)b * C * L;
    const bool interior = (l0 >= 16) && (l0 + 20 <= L);
    if (interior) {
        const float* xw = xb + (l0 - 16);
#pragma unroll 2
        for (int i = 0; i < C; ++i) {
            float win[FB_WIN];
            const floatx4* p = reinterpret_cast<const floatx4*>(xw + (long)i * L);
#pragma unroll
            for (int j = 0; j < FB_WIN / 4; ++j)
                reinterpret_cast<floatx4*>(win)[j] = p[j];
            const float* wp = w + i * K;
#pragma unroll
            for (int k = 0; k < K; ++k) {
                const float wk = wp[k];
#pragma unroll
                for (int r = 0; r < FB_R; ++r)
                    acc[r] += wk * win[r + 31 - k];
            }
        }
    } else {
        for (int i = 0; i < C; ++i) {
            const float* xi = xb + (long)i * L;
            float win[FB_WIN];
#pragma unroll
            for (int j = 0; j < FB_WIN; ++j) {
                const int g = l0 - 16 + j;
                win[j] = (g >= 0 && g < L) ? xi[g] : 0.f;
            }
            const float* wp = w + i * K;
#pragma unroll
            for (int k = 0; k < K; ++k) {
                const float wk = wp[k];
#pragma unroll
                for (int r = 0; r < FB_R; ++r)
                    acc[r] += wk * win[r + 31 - k];
            }
        }
    }
    float* op = out + (long)b * C * L + l0;
    floatx4 v; v.x = acc[0]; v.y = acc[1]; v.z = acc[2]; v.w = acc[3];
#pragma unroll
    for (int o = 0; o < C; ++o)
        __builtin_nontemporal_store(v, reinterpret_cast<floatx4*>(op + (long)o * L));
}

extern "C" void kernel_launch(void* const* d_in, const int* in_sizes, int n_in,
                              void* d_out, int out_size, void* d_ws, size_t ws_size,
                              hipStream_t stream) {
    const float* x = (const float*)d_in[0];   // [B, C, L] fp32
    const float* w = (const float*)d_in[1];   // [C, C, K] fp32; o=0 slice used
    float* out = (float*)d_out;               // [B, C, L] fp32

    const size_t sp_bytes = (size_t)CG * BATCH * L * sizeof(float);   // 8 MB
    if (ws_size >= sp_bytes) {
        float* Sp = (float*)d_ws;
        dim3 grid1(L / BTILE, BATCH, CG);         // 1024 blocks, 4 waves each
        computeS_kernel<<<grid1, NT, 0, stream>>>(x, w, Sp);
        dim3 grid2(L / 256, BATCH);               // 2048 blocks
        broadcast_kernel<<<grid2, NT, 0, stream>>>(Sp, out);
    } else {
        dim3 grid(L / FB_TILE, BATCH);
        fused_kernel<<<grid, NT, 0, stream>>>(x, w, out);
    }
}